// Round 6
// baseline (243.931 us; speedup 1.0000x reference)
//
#include <hip/hip_runtime.h>
#include <hip/hip_bf16.h>
#include <stdint.h>

#define MB_ 8192
#define FD  512
#define OD  512
#define KD  8704     // F*16 + F (basis + residual)
#define KBASIS 8192
// bt2 tiled geometry: chunk(ct, ks, o) ; ks in [0,1088), o in [0,128), 16B chunks
#define BT_KS   1088
#define BT_CHUNKS_PER_CT (BT_KS * 128)          // 139264
#define BT_BYTES_PER_CT  (BT_CHUNKS_PER_CT * 16) // 2228224

typedef __attribute__((ext_vector_type(4))) float f32x4;
typedef __attribute__((ext_vector_type(8))) short bf16x8;
typedef __attribute__((ext_vector_type(4))) unsigned int u32x4;
typedef __attribute__((ext_vector_type(2))) unsigned int u32x2;

__device__ __forceinline__ void gload_lds16(const void* g, void* l) {
  __builtin_amdgcn_global_load_lds((const __attribute__((address_space(1))) void*)g,
                                   (__attribute__((address_space(3))) void*)l,
                                   16, 0, 0);
}

__device__ __forceinline__ uint32_t bf_rtn(float f) {
  uint32_t u = __float_as_uint(f);
  return (u + 0x7fffu + ((u >> 16) & 1u)) >> 16;
}

// packed bf16 pair (a in low 16, b in high 16), round-to-nearest-even
__device__ __forceinline__ uint32_t pk(float a, float b) {
  return bf_rtn(a) | (bf_rtn(b) << 16);
}

// ---------------- phase 1: t = tanh(x) fp32, xbf = bf16(x) ----------------
__global__ __launch_bounds__(256) void k_tanh(const float* __restrict__ x,
                                              float* __restrict__ t,
                                              uint16_t* __restrict__ xbf) {
  int i = blockIdx.x * 256 + threadIdx.x;   // 0 .. 2^20-1, 4 elems each
  f32x4 v = ((const f32x4*)x)[i];
  f32x4 tv;
  tv[0] = tanhf(v[0]); tv[1] = tanhf(v[1]);
  tv[2] = tanhf(v[2]); tv[3] = tanhf(v[3]);
  ((f32x4*)t)[i] = tv;
  u32x2 p;
  p[0] = pk(v[0], v[1]);
  p[1] = pk(v[2], v[3]);
  ((u32x2*)xbf)[i] = p;
}

// ---------------- phase 2: bt2 tiled repack (PROVEN round 4) ----------------
// chunk(ct, ks, o) holds bf16 Bt[ct*128+o][ks*8 .. +8)
// where Bt[o][i*16+n] = coeffs[i,o,n] ; Bt[o][8192+i] = bw[i,o]
__global__ __launch_bounds__(256) void k_bt(const float* __restrict__ coeffs,
                                            const float* __restrict__ bw,
                                            uint16_t* __restrict__ bt2,
                                            float* __restrict__ out) {
  int tid = blockIdx.x * 256 + threadIdx.x;  // 0..262143
  {
    int o = tid & 511, i = tid >> 9;
    const f32x4* src = (const f32x4*)(coeffs + (((size_t)(i * 512 + o)) << 4));
    f32x4 c0 = src[0], c1 = src[1], c2 = src[2], c3 = src[3];
    u32x4 qa, qb;
    qa[0] = pk(c0[0], c0[1]);
    qa[1] = pk(c0[2], c0[3]);
    qa[2] = pk(c1[0], c1[1]);
    qa[3] = pk(c1[2], c1[3]);
    qb[0] = pk(c2[0], c2[1]);
    qb[1] = pk(c2[2], c2[3]);
    qb[2] = pk(c3[0], c3[1]);
    qb[3] = pk(c3[2], c3[3]);
    size_t cidx = (size_t)(o >> 7) * BT_CHUNKS_PER_CT + (size_t)(2 * i) * 128 + (o & 127);
    u32x4* base = (u32x4*)bt2;
    base[cidx]       = qa;   // kslot 2i   (n=0..7)
    base[cidx + 128] = qb;   // kslot 2i+1 (n=8..15)
  }
  {
    int o2 = tid >> 9, i2 = tid & 511;
    size_t cidx = (size_t)(o2 >> 7) * BT_CHUNKS_PER_CT + (size_t)(1024 + (i2 >> 3)) * 128 + (o2 & 127);
    bt2[cidx * 8 + (i2 & 7)] = (uint16_t)bf_rtn(bw[i2 * 512 + o2]);
  }
  if (tid == 0) out[(size_t)MB_ * OD] = 0.0f;   // kl output
}

// ---------------- phase 3: fused GEMM, register-A ---------------------------
// C[8192,512] = A[8192,8704] @ B[8704,512].
// B panel: k-major LDS, linear gload copy from tiled bt2 (PROVEN round 4).
// A operand: computed per-lane IN REGISTERS — no A LDS at all.
//   Fragment af[h][m] for lane l: row = wr*32 + m*16 + (l&15),
//   k = h*32 + (l>>4)*8 + j  ->  basis: T_{n0+j}(t[row][fb+2h+((l>>4)>>1)]),
//   n0 = ((l>>4)&1)*8 ; residual: 8 consecutive bf16 of xbf[row].
__global__ __launch_bounds__(512, 4) void k_gemm(const float* __restrict__ t,
                                                 const uint16_t* __restrict__ xbf,
                                                 const uint16_t* __restrict__ bt2,
                                                 float* __restrict__ out) {
  __shared__ __align__(128) char lds[32768];  // B panel x2 (dbuf), 16KB each

  const int tid  = threadIdx.x;
  const int lane = tid & 63;
  const int wid  = tid >> 6;        // 0..7
  const int wr   = wid >> 1;        // 0..3 (row group of 32)
  const int wc   = wid & 1;         // 0..1 (col group of 64)
  const int l15  = lane & 15, l4 = lane >> 4;
  const bool hiH = (l4 & 1) != 0;   // which T-half this lane holds
  const int fq   = l4 >> 1;         // feature sub-offset 0..1

  // bijective XCD swizzle: each XCD gets 8 row-tiles x 4 col-tiles
  int bx  = blockIdx.x;             // 0..255
  int idx = bx >> 3;
  int rt  = (bx & 7) * 8 + (idx >> 2);   // 0..63
  int ct  = idx & 3;                     // 0..3
  const int brow = rt << 7, bcol = ct << 7;

  const int tsk0 = wid * 2;
  const char* btbase = (const char*)bt2 + (size_t)ct * BT_BYTES_PER_CT;
  const int r0 = brow + wr * 32 + l15;               // m=0 row of this lane
  const float*    t0 = t   + (size_t)r0 * FD;
  const float*    t1 = t0  + (size_t)16 * FD;        // m=1 row
  const uint16_t* x0 = xbf + (size_t)r0 * FD;
  const uint16_t* x1 = x0  + (size_t)16 * FD;

  f32x4 acc[2][4];
#pragma unroll
  for (int m = 0; m < 2; ++m)
#pragma unroll
    for (int n = 0; n < 4; ++n) acc[m][n] = (f32x4)0.0f;

  auto stageB = [&](int k0, int buf) {          // linear copy from tiled bt2
    char* base = lds + buf * 16384;
    const char* g = btbase + (size_t)k0 * 256 + (size_t)lane * 16;
#pragma unroll
    for (int j = 0; j < 2; ++j) {
      int tsk = tsk0 + j;
      gload_lds16(g + tsk * 1024, base + tsk * 1024);
    }
  };

  // Chebyshev chain -> this lane's 8-element fragment (T_{n0}..T_{n0+7})
  auto chainfrag = [&](float tv) -> u32x4 {
    float c2 = tv + tv;
    float T0 = 1.0f, T1 = tv;
    float T2  = __builtin_fmaf(c2, T1,  -T0);
    float T3  = __builtin_fmaf(c2, T2,  -T1);
    float T4  = __builtin_fmaf(c2, T3,  -T2);
    float T5  = __builtin_fmaf(c2, T4,  -T3);
    float T6  = __builtin_fmaf(c2, T5,  -T4);
    float T7  = __builtin_fmaf(c2, T6,  -T5);
    float T8  = __builtin_fmaf(c2, T7,  -T6);
    float T9  = __builtin_fmaf(c2, T8,  -T7);
    float T10 = __builtin_fmaf(c2, T9,  -T8);
    float T11 = __builtin_fmaf(c2, T10, -T9);
    float T12 = __builtin_fmaf(c2, T11, -T10);
    float T13 = __builtin_fmaf(c2, T12, -T11);
    float T14 = __builtin_fmaf(c2, T13, -T12);
    float T15 = __builtin_fmaf(c2, T14, -T13);
    u32x4 r;
    r[0] = hiH ? pk(T8,  T9)  : pk(T0, T1);
    r[1] = hiH ? pk(T10, T11) : pk(T2, T3);
    r[2] = hiH ? pk(T12, T13) : pk(T4, T5);
    r[3] = hiH ? pk(T14, T15) : pk(T6, T7);
    return r;
  };

  stageB(0, 0);
  for (int step = 0; step < 136; ++step) {
    int buf = step & 1;
    int k1  = step << 6;
    bool basis = (k1 < KBASIS);

    float tva, tvb, tvc, tvd;              // t values (basis steps)
    u32x4 af00, af10, af01, af11;          // af[h][m]
    if (basis) {
      int fb = step << 2;                  // feature base k1/16
      tva = t0[fb + fq];                   // h=0, m=0
      tvb = t0[fb + 2 + fq];               // h=1, m=0
      tvc = t1[fb + fq];                   // h=0, m=1
      tvd = t1[fb + 2 + fq];               // h=1, m=1
    } else {
      int kres = (k1 - KBASIS) + l4 * 8;
      af00 = *(const u32x4*)(x0 + kres);
      af10 = *(const u32x4*)(x0 + kres + 32);
      af01 = *(const u32x4*)(x1 + kres);
      af11 = *(const u32x4*)(x1 + kres + 32);
    }

    __syncthreads();                       // stage into buf complete
    if (step < 135) stageB((step + 1) << 6, buf ^ 1);

    if (basis) {
      af00 = chainfrag(tva);
      af10 = chainfrag(tvb);
      af01 = chainfrag(tvc);
      af11 = chainfrag(tvd);
    }

    const char* bb = lds + buf * 16384;
    bf16x8 b[2][4];
#pragma unroll
    for (int h = 0; h < 2; ++h) {
      int ks = 4 * h + l4;                 // kslot = k/8
#pragma unroll
      for (int n = 0; n < 4; ++n) {
        int row = wc * 64 + n * 16 + l15;
        b[h][n] = *(const bf16x8*)(bb + ks * 2048 + row * 16);
      }
    }
    bf16x8 a00 = *(const bf16x8*)&af00;
    bf16x8 a01 = *(const bf16x8*)&af01;
    bf16x8 a10 = *(const bf16x8*)&af10;
    bf16x8 a11 = *(const bf16x8*)&af11;
#pragma unroll
    for (int n = 0; n < 4; ++n) {
      acc[0][n] = __builtin_amdgcn_mfma_f32_16x16x32_bf16(a00, b[0][n], acc[0][n], 0, 0, 0);
      acc[1][n] = __builtin_amdgcn_mfma_f32_16x16x32_bf16(a01, b[0][n], acc[1][n], 0, 0, 0);
      acc[0][n] = __builtin_amdgcn_mfma_f32_16x16x32_bf16(a10, b[1][n], acc[0][n], 0, 0, 0);
      acc[1][n] = __builtin_amdgcn_mfma_f32_16x16x32_bf16(a11, b[1][n], acc[1][n], 0, 0, 0);
    }
  }

  // epilogue: C/D layout col=l&15, row=(l>>4)*4+r  [m89]
#pragma unroll
  for (int m = 0; m < 2; ++m)
#pragma unroll
    for (int n = 0; n < 4; ++n)
#pragma unroll
      for (int r = 0; r < 4; ++r) {
        int grow = brow + wr * 32 + m * 16 + l4 * 4 + r;
        int gcol = bcol + wc * 64 + n * 16 + l15;
        out[(size_t)grow * OD + gcol] = acc[m][n][r];
      }
}

extern "C" void kernel_launch(void* const* d_in, const int* in_sizes, int n_in,
                              void* d_out, int out_size, void* d_ws, size_t ws_size,
                              hipStream_t stream) {
  const float* x      = (const float*)d_in[0];
  const float* coeffs = (const float*)d_in[1];
  const float* bw     = (const float*)d_in[2];
  float* out = (float*)d_out;
  char* ws = (char*)d_ws;

  float*    t   = (float*)ws;                                  // 16 MB fp32 tanh
  uint16_t* xbf = (uint16_t*)(ws + (size_t)16777216);          // 8 MB bf16 x
  uint16_t* bt2 = (uint16_t*)(ws + (size_t)16777216 + 8388608);// 8.5 MB tiled B

  k_tanh<<<4096, 256, 0, stream>>>(x, t, xbf);
  k_bt<<<1024, 256, 0, stream>>>(coeffs, bw, bt2, out);
  k_gemm<<<256, 512, 0, stream>>>(t, xbf, bt2, out);
}

// Round 7
// 217.813 us; speedup vs baseline: 1.1199x; 1.1199x over previous
//
#include <hip/hip_runtime.h>
#include <hip/hip_bf16.h>
#include <stdint.h>

#define MB_ 8192
#define FD  512
#define OD  512
#define KD  8704     // F*16 + F (basis + residual)
#define KBASIS 8192
// bt2 tiled geometry: chunk(ct, ks, o) ; ks in [0,1088), o in [0,128), 16B chunks
#define BT_KS   1088
#define BT_CHUNKS_PER_CT (BT_KS * 128)          // 139264
#define BT_BYTES_PER_CT  (BT_CHUNKS_PER_CT * 16) // 2228224

typedef __attribute__((ext_vector_type(4))) float f32x4;
typedef __attribute__((ext_vector_type(8))) short bf16x8;
typedef __attribute__((ext_vector_type(4))) unsigned int u32x4;
typedef __attribute__((ext_vector_type(2))) unsigned int u32x2;

__device__ __forceinline__ void gload_lds16(const void* g, void* l) {
  __builtin_amdgcn_global_load_lds((const __attribute__((address_space(1))) void*)g,
                                   (__attribute__((address_space(3))) void*)l,
                                   16, 0, 0);
}

__device__ __forceinline__ uint32_t bf_rtn(float f) {
  uint32_t u = __float_as_uint(f);
  return (u + 0x7fffu + ((u >> 16) & 1u)) >> 16;
}

// packed bf16 pair via v_cvt_pk_bf16_f32 (compiler-emitted from the intrinsic;
// m240: do NOT hand-write the asm). RNE — identical results to bf_rtn.
__device__ __forceinline__ uint32_t pk(float a, float b) {
  float2 v; v.x = a; v.y = b;
  __hip_bfloat162 h = __float22bfloat162_rn(v);
  uint32_t r;
  __builtin_memcpy(&r, &h, 4);
  return r;
}

// ---------------- phase 1: t = tanh(x) fp32, xbf = bf16(x) ----------------
__global__ __launch_bounds__(256) void k_tanh(const float* __restrict__ x,
                                              float* __restrict__ t,
                                              uint16_t* __restrict__ xbf) {
  int i = blockIdx.x * 256 + threadIdx.x;   // 0 .. 2^20-1, 4 elems each
  f32x4 v = ((const f32x4*)x)[i];
  f32x4 tv;
  tv[0] = tanhf(v[0]); tv[1] = tanhf(v[1]);
  tv[2] = tanhf(v[2]); tv[3] = tanhf(v[3]);
  ((f32x4*)t)[i] = tv;
  u32x2 p;
  p[0] = pk(v[0], v[1]);
  p[1] = pk(v[2], v[3]);
  ((u32x2*)xbf)[i] = p;
}

// ---------------- phase 2: bt2 tiled repack (PROVEN round 4) ----------------
// chunk(ct, ks, o) holds bf16 Bt[ct*128+o][ks*8 .. +8)
// where Bt[o][i*16+n] = coeffs[i,o,n] ; Bt[o][8192+i] = bw[i,o]
__global__ __launch_bounds__(256) void k_bt(const float* __restrict__ coeffs,
                                            const float* __restrict__ bw,
                                            uint16_t* __restrict__ bt2,
                                            float* __restrict__ out) {
  int tid = blockIdx.x * 256 + threadIdx.x;  // 0..262143
  {
    int o = tid & 511, i = tid >> 9;
    const f32x4* src = (const f32x4*)(coeffs + (((size_t)(i * 512 + o)) << 4));
    f32x4 c0 = src[0], c1 = src[1], c2 = src[2], c3 = src[3];
    u32x4 qa, qb;
    qa[0] = pk(c0[0], c0[1]);
    qa[1] = pk(c0[2], c0[3]);
    qa[2] = pk(c1[0], c1[1]);
    qa[3] = pk(c1[2], c1[3]);
    qb[0] = pk(c2[0], c2[1]);
    qb[1] = pk(c2[2], c2[3]);
    qb[2] = pk(c3[0], c3[1]);
    qb[3] = pk(c3[2], c3[3]);
    size_t cidx = (size_t)(o >> 7) * BT_CHUNKS_PER_CT + (size_t)(2 * i) * 128 + (o & 127);
    u32x4* base = (u32x4*)bt2;
    base[cidx]       = qa;   // kslot 2i   (n=0..7)
    base[cidx + 128] = qb;   // kslot 2i+1 (n=8..15)
  }
  {
    int o2 = tid >> 9, i2 = tid & 511;
    size_t cidx = (size_t)(o2 >> 7) * BT_CHUNKS_PER_CT + (size_t)(1024 + (i2 >> 3)) * 128 + (o2 & 127);
    bt2[cidx * 8 + (i2 & 7)] = (uint16_t)bf_rtn(bw[i2 * 512 + o2]);
  }
  if (tid == 0) out[(size_t)MB_ * OD] = 0.0f;   // kl output
}

// ---------------- phase 3: fused GEMM, register-A ---------------------------
// C[8192,512] = A[8192,8704] @ B[8704,512].
// B panel: k-major LDS, linear gload copy from tiled bt2 (PROVEN rounds 4/6).
// A operand: computed per-lane IN REGISTERS; all A-side global inputs are
// PREFETCHED ONE STEP AHEAD, issued right after the barrier so their latency
// hides under a full step of chains+MFMA (round-6 fix: pre-barrier loads were
// drained serially by the barrier's vmcnt(0) every step).
__global__ __launch_bounds__(512, 4) void k_gemm(const float* __restrict__ t,
                                                 const uint16_t* __restrict__ xbf,
                                                 const uint16_t* __restrict__ bt2,
                                                 float* __restrict__ out) {
  __shared__ __align__(128) char lds[32768];  // B panel x2 (dbuf), 16KB each

  const int tid  = threadIdx.x;
  const int lane = tid & 63;
  const int wid  = tid >> 6;        // 0..7
  const int wr   = wid >> 1;        // 0..3 (row group of 32)
  const int wc   = wid & 1;         // 0..1 (col group of 64)
  const int l15  = lane & 15, l4 = lane >> 4;
  const bool hiH = (l4 & 1) != 0;   // which T-half this lane holds
  const int fq   = l4 >> 1;         // feature sub-offset 0..1

  // bijective XCD swizzle: each XCD gets 8 row-tiles x 4 col-tiles
  int bx  = blockIdx.x;             // 0..255
  int idx = bx >> 3;
  int rt  = (bx & 7) * 8 + (idx >> 2);   // 0..63
  int ct  = idx & 3;                     // 0..3
  const int brow = rt << 7, bcol = ct << 7;

  const int tsk0 = wid * 2;
  const char* btbase = (const char*)bt2 + (size_t)ct * BT_BYTES_PER_CT;
  const int r0 = brow + wr * 32 + l15;               // m=0 row of this lane
  const float*    t0 = t   + (size_t)r0 * FD;
  const float*    t1 = t0  + (size_t)16 * FD;        // m=1 row
  const uint16_t* x0 = xbf + (size_t)r0 * FD;
  const uint16_t* x1 = x0  + (size_t)16 * FD;

  f32x4 acc[2][4];
#pragma unroll
  for (int m = 0; m < 2; ++m)
#pragma unroll
    for (int n = 0; n < 4; ++n) acc[m][n] = (f32x4)0.0f;

  auto stageB = [&](int k0, int buf) {          // linear copy from tiled bt2
    char* base = lds + buf * 16384;
    const char* g = btbase + (size_t)k0 * 256 + (size_t)lane * 16;
#pragma unroll
    for (int j = 0; j < 2; ++j) {
      int tsk = tsk0 + j;
      gload_lds16(g + tsk * 1024, base + tsk * 1024);
    }
  };

  // Chebyshev chain -> this lane's 8-element fragment (T_{n0}..T_{n0+7})
  auto chainfrag = [&](float tv) -> u32x4 {
    float c2 = tv + tv;
    float T0 = 1.0f, T1 = tv;
    float T2  = __builtin_fmaf(c2, T1,  -T0);
    float T3  = __builtin_fmaf(c2, T2,  -T1);
    float T4  = __builtin_fmaf(c2, T3,  -T2);
    float T5  = __builtin_fmaf(c2, T4,  -T3);
    float T6  = __builtin_fmaf(c2, T5,  -T4);
    float T7  = __builtin_fmaf(c2, T6,  -T5);
    float T8  = __builtin_fmaf(c2, T7,  -T6);
    float T9  = __builtin_fmaf(c2, T8,  -T7);
    float T10 = __builtin_fmaf(c2, T9,  -T8);
    float T11 = __builtin_fmaf(c2, T10, -T9);
    float T12 = __builtin_fmaf(c2, T11, -T10);
    float T13 = __builtin_fmaf(c2, T12, -T11);
    float T14 = __builtin_fmaf(c2, T13, -T12);
    float T15 = __builtin_fmaf(c2, T14, -T13);
    u32x4 r;
    r[0] = hiH ? pk(T8,  T9)  : pk(T0, T1);
    r[1] = hiH ? pk(T10, T11) : pk(T2, T3);
    r[2] = hiH ? pk(T12, T13) : pk(T4, T5);
    r[3] = hiH ? pk(T14, T15) : pk(T6, T7);
    return r;
  };

  // prologue: prefetch A-inputs for step 0; stage B for step 0
  float pta = t0[fq], ptb = t0[2 + fq], ptc = t1[fq], ptd = t1[2 + fq];
  u32x4 pf0 = {}, pf1 = {}, pf2 = {}, pf3 = {};
  stageB(0, 0);

  for (int step = 0; step < 136; ++step) {
    int buf = step & 1;
    bool basis = step < 128;                     // KBASIS/64 = 128

    // consume this step's prefetched A-inputs (copy before overwrite)
    float tva = pta, tvb = ptb, tvc = ptc, tvd = ptd;
    u32x4 af00 = pf0, af10 = pf1, af01 = pf2, af11 = pf3;

    __syncthreads();                 // drains stageB(step) + last prefetches

    if (step < 135) {
      stageB((step + 1) << 6, buf ^ 1);
      if (step + 1 < 128) {          // prefetch t for next basis step
        int fb = (step + 1) << 2;
        pta = t0[fb + fq];  ptb = t0[fb + 2 + fq];
        ptc = t1[fb + fq];  ptd = t1[fb + 2 + fq];
      } else {                       // prefetch xbf frags for next residual step
        int kres = ((step + 1 - 128) << 6) + l4 * 8;
        pf0 = *(const u32x4*)(x0 + kres);
        pf1 = *(const u32x4*)(x0 + kres + 32);
        pf2 = *(const u32x4*)(x1 + kres);
        pf3 = *(const u32x4*)(x1 + kres + 32);
      }
    }

    if (basis) {
      af00 = chainfrag(tva);
      af10 = chainfrag(tvb);
      af01 = chainfrag(tvc);
      af11 = chainfrag(tvd);
    }

    const char* bb = lds + buf * 16384;
    bf16x8 b[2][4];
#pragma unroll
    for (int h = 0; h < 2; ++h) {
      int ks = 4 * h + l4;                 // kslot = k/8
#pragma unroll
      for (int n = 0; n < 4; ++n) {
        int row = wc * 64 + n * 16 + l15;
        b[h][n] = *(const bf16x8*)(bb + ks * 2048 + row * 16);
      }
    }
    bf16x8 a00 = *(const bf16x8*)&af00;
    bf16x8 a01 = *(const bf16x8*)&af01;
    bf16x8 a10 = *(const bf16x8*)&af10;
    bf16x8 a11 = *(const bf16x8*)&af11;
#pragma unroll
    for (int n = 0; n < 4; ++n) {
      acc[0][n] = __builtin_amdgcn_mfma_f32_16x16x32_bf16(a00, b[0][n], acc[0][n], 0, 0, 0);
      acc[1][n] = __builtin_amdgcn_mfma_f32_16x16x32_bf16(a01, b[0][n], acc[1][n], 0, 0, 0);
      acc[0][n] = __builtin_amdgcn_mfma_f32_16x16x32_bf16(a10, b[1][n], acc[0][n], 0, 0, 0);
      acc[1][n] = __builtin_amdgcn_mfma_f32_16x16x32_bf16(a11, b[1][n], acc[1][n], 0, 0, 0);
    }
  }

  // epilogue: C/D layout col=l&15, row=(l>>4)*4+r  [m89]
#pragma unroll
  for (int m = 0; m < 2; ++m)
#pragma unroll
    for (int n = 0; n < 4; ++n)
#pragma unroll
      for (int r = 0; r < 4; ++r) {
        int grow = brow + wr * 32 + m * 16 + l4 * 4 + r;
        int gcol = bcol + wc * 64 + n * 16 + l15;
        out[(size_t)grow * OD + gcol] = acc[m][n][r];
      }
}

extern "C" void kernel_launch(void* const* d_in, const int* in_sizes, int n_in,
                              void* d_out, int out_size, void* d_ws, size_t ws_size,
                              hipStream_t stream) {
  const float* x      = (const float*)d_in[0];
  const float* coeffs = (const float*)d_in[1];
  const float* bw     = (const float*)d_in[2];
  float* out = (float*)d_out;
  char* ws = (char*)d_ws;

  float*    t   = (float*)ws;                                  // 16 MB fp32 tanh
  uint16_t* xbf = (uint16_t*)(ws + (size_t)16777216);          // 8 MB bf16 x
  uint16_t* bt2 = (uint16_t*)(ws + (size_t)16777216 + 8388608);// 8.5 MB tiled B

  k_tanh<<<4096, 256, 0, stream>>>(x, t, xbf);
  k_bt<<<1024, 256, 0, stream>>>(coeffs, bw, bt2, out);
  k_gemm<<<256, 512, 0, stream>>>(t, xbf, bt2, out);
}

// Round 9
// 141.611 us; speedup vs baseline: 1.7225x; 1.5381x over previous
//
#include <hip/hip_runtime.h>
#include <hip/hip_bf16.h>
#include <stdint.h>

#define MB_ 8192
#define FD  512
#define OD  512
#define KD  8704     // F*16 + F (basis + residual)
#define KBASIS 8192
// bt2 tiled geometry: chunk(ct, ks, o) ; ks in [0,1088), o in [0,128), 16B chunks
#define BT_KS   1088
#define BT_CHUNKS_PER_CT (BT_KS * 128)          // 139264
#define BT_BYTES_PER_CT  (BT_CHUNKS_PER_CT * 16) // 2228224

typedef __attribute__((ext_vector_type(4))) float f32x4;
typedef __attribute__((ext_vector_type(8))) short bf16x8;
typedef __attribute__((ext_vector_type(4))) unsigned int u32x4;
typedef __attribute__((ext_vector_type(2))) unsigned int u32x2;

__device__ __forceinline__ void gload_lds16(const void* g, void* l) {
  __builtin_amdgcn_global_load_lds((const __attribute__((address_space(1))) void*)g,
                                   (__attribute__((address_space(3))) void*)l,
                                   16, 0, 0);
}

__device__ __forceinline__ uint32_t bf_rtn(float f) {
  uint32_t u = __float_as_uint(f);
  return (u + 0x7fffu + ((u >> 16) & 1u)) >> 16;
}

// packed bf16 pair (a in low 16, b in high 16) via HW v_cvt_pk_bf16_f32
// (T12 recipe: no builtin on gfx950; pure-VALU asm, RNE)
__device__ __forceinline__ uint32_t pk(float a, float b) {
  uint32_t r;
  asm("v_cvt_pk_bf16_f32 %0, %1, %2" : "=v"(r) : "v"(a), "v"(b));
  return r;
}

// ---------------- phase 1: t = tanh(x) fp32, xbf = bf16(x) ----------------
__global__ __launch_bounds__(256) void k_tanh(const float* __restrict__ x,
                                              float* __restrict__ t,
                                              uint16_t* __restrict__ xbf) {
  int i = blockIdx.x * 256 + threadIdx.x;   // 0 .. 2^20-1, 4 elems each
  f32x4 v = ((const f32x4*)x)[i];
  f32x4 tv;
  tv[0] = tanhf(v[0]); tv[1] = tanhf(v[1]);
  tv[2] = tanhf(v[2]); tv[3] = tanhf(v[3]);
  ((f32x4*)t)[i] = tv;
  u32x2 p;
  p[0] = pk(v[0], v[1]);
  p[1] = pk(v[2], v[3]);
  ((u32x2*)xbf)[i] = p;
}

// ---------------- phase 2: bt2 tiled repack (PROVEN rounds 4/6/7) -----------
// chunk(ct, ks, o) holds bf16 Bt[ct*128+o][ks*8 .. +8)
// where Bt[o][i*16+n] = coeffs[i,o,n] ; Bt[o][8192+i] = bw[i,o]
__global__ __launch_bounds__(256) void k_bt(const float* __restrict__ coeffs,
                                            const float* __restrict__ bw,
                                            uint16_t* __restrict__ bt2,
                                            float* __restrict__ out) {
  int tid = blockIdx.x * 256 + threadIdx.x;  // 0..262143
  {
    int o = tid & 511, i = tid >> 9;
    const f32x4* src = (const f32x4*)(coeffs + (((size_t)(i * 512 + o)) << 4));
    f32x4 c0 = src[0], c1 = src[1], c2 = src[2], c3 = src[3];
    u32x4 qa, qb;
    qa[0] = pk(c0[0], c0[1]);
    qa[1] = pk(c0[2], c0[3]);
    qa[2] = pk(c1[0], c1[1]);
    qa[3] = pk(c1[2], c1[3]);
    qb[0] = pk(c2[0], c2[1]);
    qb[1] = pk(c2[2], c2[3]);
    qb[2] = pk(c3[0], c3[1]);
    qb[3] = pk(c3[2], c3[3]);
    size_t cidx = (size_t)(o >> 7) * BT_CHUNKS_PER_CT + (size_t)(2 * i) * 128 + (o & 127);
    u32x4* base = (u32x4*)bt2;
    base[cidx]       = qa;   // kslot 2i   (n=0..7)
    base[cidx + 128] = qb;   // kslot 2i+1 (n=8..15)
  }
  {
    int o2 = tid >> 9, i2 = tid & 511;
    size_t cidx = (size_t)(o2 >> 7) * BT_CHUNKS_PER_CT + (size_t)(1024 + (i2 >> 3)) * 128 + (o2 & 127);
    bt2[cidx * 8 + (i2 & 7)] = (uint16_t)bf_rtn(bw[i2 * 512 + o2]);
  }
  if (tid == 0) out[(size_t)MB_ * OD] = 0.0f;   // kl output
}

// ---------------- phase 3: fused GEMM, register-A ---------------------------
// C[8192,512] = A[8192,8704] @ B[8704,512].
// B panel: k-major LDS, linear gload copy from tiled bt2 (PROVEN rounds 4/6/7).
// A basis: per-lane register chains; t-slice (128 rows x 4 feats = 2KB/step)
// staged to LDS via 2 global_load_lds; packs via HW v_cvt_pk_bf16_f32.
// ROUND-9 FIX: residual prefetch regs are SNAPSHOTTED at loop top before the
// next-step prefetch overwrites them (round-8 consumed post-overwrite data:
// residual K-slices shifted by one step -> absmax 8.06).
__global__ __launch_bounds__(512, 4) void k_gemm(const float* __restrict__ t,
                                                 const uint16_t* __restrict__ xbf,
                                                 const uint16_t* __restrict__ bt2,
                                                 float* __restrict__ out) {
  __shared__ __align__(128) char lds[36864];  // B dbuf 2x16KB | t dbuf 2x2KB

  const int tid  = threadIdx.x;
  const int lane = tid & 63;
  const int wid  = tid >> 6;        // 0..7
  const int wr   = wid >> 1;        // 0..3 (row group of 32)
  const int wc   = wid & 1;         // 0..1 (col group of 64)
  const int l15  = lane & 15, l4 = lane >> 4;
  const bool hiH = (l4 & 1) != 0;   // which T-half this lane holds
  const int fq   = l4 >> 1;         // feature sub-offset 0..1

  // bijective XCD swizzle: each XCD gets 8 row-tiles x 4 col-tiles
  int bx  = blockIdx.x;             // 0..255
  int idx = bx >> 3;
  int rt  = (bx & 7) * 8 + (idx >> 2);   // 0..63
  int ct  = idx & 3;                     // 0..3
  const int brow = rt << 7, bcol = ct << 7;

  const int tsk0 = wid * 2;
  const char* btbase = (const char*)bt2 + (size_t)ct * BT_BYTES_PER_CT;
  const int r0 = brow + wr * 32 + l15;               // m=0 row of this lane
  const uint16_t* x0 = xbf + (size_t)r0 * FD;
  const uint16_t* x1 = x0  + (size_t)16 * FD;        // m=1 row

  f32x4 acc[2][4];
#pragma unroll
  for (int m = 0; m < 2; ++m)
#pragma unroll
    for (int n = 0; n < 4; ++n) acc[m][n] = (f32x4)0.0f;

  auto stageB = [&](int k0, int buf) {          // linear copy from tiled bt2
    char* base = lds + buf * 16384;
    const char* g = btbase + (size_t)k0 * 256 + (size_t)lane * 16;
#pragma unroll
    for (int j = 0; j < 2; ++j) {
      int tsk = tsk0 + j;
      gload_lds16(g + tsk * 1024, base + tsk * 1024);
    }
  };
  // stage t[brow..brow+127][4*stepn .. +4) (2KB) -> LDS t panel
  auto stageT = [&](int stepn, int buf) {
    if (wid < 2) {
      const char* g = (const char*)t +
          (((size_t)(brow + wid * 64 + lane) * FD + (stepn << 2)) << 2);
      gload_lds16(g, lds + 32768 + buf * 2048 + wid * 1024 + lane * 16);
    }
  };

  // Chebyshev chain -> this lane's 8-element fragment (T_{n0}..T_{n0+7});
  // select floats (cndmask) then 4 HW packs.
  auto chainfrag = [&](float tv) -> u32x4 {
    float c2 = tv + tv;
    float T0 = 1.0f, T1 = tv;
    float T2  = __builtin_fmaf(c2, T1,  -T0);
    float T3  = __builtin_fmaf(c2, T2,  -T1);
    float T4  = __builtin_fmaf(c2, T3,  -T2);
    float T5  = __builtin_fmaf(c2, T4,  -T3);
    float T6  = __builtin_fmaf(c2, T5,  -T4);
    float T7  = __builtin_fmaf(c2, T6,  -T5);
    float T8  = __builtin_fmaf(c2, T7,  -T6);
    float T9  = __builtin_fmaf(c2, T8,  -T7);
    float T10 = __builtin_fmaf(c2, T9,  -T8);
    float T11 = __builtin_fmaf(c2, T10, -T9);
    float T12 = __builtin_fmaf(c2, T11, -T10);
    float T13 = __builtin_fmaf(c2, T12, -T11);
    float T14 = __builtin_fmaf(c2, T13, -T12);
    float T15 = __builtin_fmaf(c2, T14, -T13);
    float s0 = hiH ? T8  : T0, s1 = hiH ? T9  : T1;
    float s2 = hiH ? T10 : T2, s3 = hiH ? T11 : T3;
    float s4 = hiH ? T12 : T4, s5 = hiH ? T13 : T5;
    float s6 = hiH ? T14 : T6, s7 = hiH ? T15 : T7;
    u32x4 r;
    r[0] = pk(s0, s1); r[1] = pk(s2, s3);
    r[2] = pk(s4, s5); r[3] = pk(s6, s7);
    return r;
  };

  // prologue: stage B and t for step 0
  stageB(0, 0);
  stageT(0, 0);
  u32x4 pf0 = {}, pf1 = {}, pf2 = {}, pf3 = {};   // residual prefetch regs

  for (int step = 0; step < 136; ++step) {
    int buf = step & 1;
    bool basis = step < 128;                     // KBASIS/64 = 128

    // snapshot THIS step's residual data BEFORE the next prefetch overwrites
    u32x4 af00 = pf0, af10 = pf1, af01 = pf2, af11 = pf3;

    __syncthreads();                 // buf fully staged (B + t)

    if (step < 135) {
      stageB((step + 1) << 6, buf ^ 1);
      if (step + 1 < 128) {
        stageT(step + 1, buf ^ 1);
      } else {                       // prefetch xbf frags for next residual step
        int kres = ((step + 1 - 128) << 6) + l4 * 8;
        pf0 = *(const u32x4*)(x0 + kres);
        pf1 = *(const u32x4*)(x0 + kres + 32);
        pf2 = *(const u32x4*)(x1 + kres);
        pf3 = *(const u32x4*)(x1 + kres + 32);
      }
    }

    if (basis) {
      const char* tb = lds + 32768 + buf * 2048;
      int ra = (wr * 32 + l15) * 16;           // m=0 row byte base
      float tva = *(const float*)(tb + ra + fq * 4);
      float tvb = *(const float*)(tb + ra + (2 + fq) * 4);
      float tvc = *(const float*)(tb + ra + 256 + fq * 4);        // +16 rows
      float tvd = *(const float*)(tb + ra + 256 + (2 + fq) * 4);
      af00 = chainfrag(tva);
      af10 = chainfrag(tvb);
      af01 = chainfrag(tvc);
      af11 = chainfrag(tvd);
    }

    const char* bb = lds + buf * 16384;
    bf16x8 b[2][4];
#pragma unroll
    for (int h = 0; h < 2; ++h) {
      int ks = 4 * h + l4;                 // kslot = k/8
#pragma unroll
      for (int n = 0; n < 4; ++n) {
        int row = wc * 64 + n * 16 + l15;
        b[h][n] = *(const bf16x8*)(bb + ks * 2048 + row * 16);
      }
    }
    bf16x8 a00 = *(const bf16x8*)&af00;
    bf16x8 a01 = *(const bf16x8*)&af01;
    bf16x8 a10 = *(const bf16x8*)&af10;
    bf16x8 a11 = *(const bf16x8*)&af11;
#pragma unroll
    for (int n = 0; n < 4; ++n) {
      acc[0][n] = __builtin_amdgcn_mfma_f32_16x16x32_bf16(a00, b[0][n], acc[0][n], 0, 0, 0);
      acc[1][n] = __builtin_amdgcn_mfma_f32_16x16x32_bf16(a01, b[0][n], acc[1][n], 0, 0, 0);
      acc[0][n] = __builtin_amdgcn_mfma_f32_16x16x32_bf16(a10, b[1][n], acc[0][n], 0, 0, 0);
      acc[1][n] = __builtin_amdgcn_mfma_f32_16x16x32_bf16(a11, b[1][n], acc[1][n], 0, 0, 0);
    }
  }

  // epilogue: C/D layout col=l&15, row=(l>>4)*4+r  [m89]
#pragma unroll
  for (int m = 0; m < 2; ++m)
#pragma unroll
    for (int n = 0; n < 4; ++n)
#pragma unroll
      for (int r = 0; r < 4; ++r) {
        int grow = brow + wr * 32 + m * 16 + l4 * 4 + r;
        int gcol = bcol + wc * 64 + n * 16 + l15;
        out[(size_t)grow * OD + gcol] = acc[m][n][r];
      }
}

extern "C" void kernel_launch(void* const* d_in, const int* in_sizes, int n_in,
                              void* d_out, int out_size, void* d_ws, size_t ws_size,
                              hipStream_t stream) {
  const float* x      = (const float*)d_in[0];
  const float* coeffs = (const float*)d_in[1];
  const float* bw     = (const float*)d_in[2];
  float* out = (float*)d_out;
  char* ws = (char*)d_ws;

  float*    t   = (float*)ws;                                  // 16 MB fp32 tanh
  uint16_t* xbf = (uint16_t*)(ws + (size_t)16777216);          // 8 MB bf16 x
  uint16_t* bt2 = (uint16_t*)(ws + (size_t)16777216 + 8388608);// 8.5 MB tiled B

  k_tanh<<<4096, 256, 0, stream>>>(x, t, xbf);
  k_bt<<<1024, 256, 0, stream>>>(coeffs, bw, bt2, out);
  k_gemm<<<256, 512, 0, stream>>>(t, xbf, bt2, out);
}

// Round 10
// 131.017 us; speedup vs baseline: 1.8618x; 1.0809x over previous
//
#include <hip/hip_runtime.h>
#include <hip/hip_bf16.h>
#include <stdint.h>

#define MB_ 8192
#define FD  512
#define OD  512
#define KD  8704     // F*16 + F (basis + residual)
#define KBASIS 8192
// bt2 tiled geometry: chunk(ct, ks, o) ; ks in [0,1088), o in [0,128), 16B chunks
#define BT_KS   1088
#define BT_CHUNKS_PER_CT (BT_KS * 128)          // 139264
#define BT_BYTES_PER_CT  (BT_CHUNKS_PER_CT * 16) // 2228224

typedef __attribute__((ext_vector_type(4))) float f32x4;
typedef __attribute__((ext_vector_type(8))) short bf16x8;
typedef __attribute__((ext_vector_type(4))) unsigned int u32x4;
typedef __attribute__((ext_vector_type(2))) unsigned int u32x2;

__device__ __forceinline__ void gload_lds16(const void* g, void* l) {
  __builtin_amdgcn_global_load_lds((const __attribute__((address_space(1))) void*)g,
                                   (__attribute__((address_space(3))) void*)l,
                                   16, 0, 0);
}

__device__ __forceinline__ uint32_t bf_rtn(float f) {
  uint32_t u = __float_as_uint(f);
  return (u + 0x7fffu + ((u >> 16) & 1u)) >> 16;
}

// packed bf16 pair (a in low 16, b in high 16) via HW v_cvt_pk_bf16_f32
__device__ __forceinline__ uint32_t pk(float a, float b) {
  uint32_t r;
  asm("v_cvt_pk_bf16_f32 %0, %1, %2" : "=v"(r) : "v"(a), "v"(b));
  return r;
}

// ---------------- phase 1: t = tanh(x) fp32, xbf = bf16(x) ----------------
__global__ __launch_bounds__(256) void k_tanh(const float* __restrict__ x,
                                              float* __restrict__ t,
                                              uint16_t* __restrict__ xbf) {
  int i = blockIdx.x * 256 + threadIdx.x;   // 0 .. 2^20-1, 4 elems each
  f32x4 v = ((const f32x4*)x)[i];
  f32x4 tv;
  tv[0] = tanhf(v[0]); tv[1] = tanhf(v[1]);
  tv[2] = tanhf(v[2]); tv[3] = tanhf(v[3]);
  ((f32x4*)t)[i] = tv;
  u32x2 p;
  p[0] = pk(v[0], v[1]);
  p[1] = pk(v[2], v[3]);
  ((u32x2*)xbf)[i] = p;
}

// ---------------- phase 2: bt2 tiled repack (PROVEN rounds 4..9) ------------
// chunk(ct, ks, o) holds bf16 Bt[ct*128+o][ks*8 .. +8)
// where Bt[o][i*16+n] = coeffs[i,o,n] ; Bt[o][8192+i] = bw[i,o]
__global__ __launch_bounds__(256) void k_bt(const float* __restrict__ coeffs,
                                            const float* __restrict__ bw,
                                            uint16_t* __restrict__ bt2,
                                            float* __restrict__ out) {
  int tid = blockIdx.x * 256 + threadIdx.x;  // 0..262143
  {
    int o = tid & 511, i = tid >> 9;
    const f32x4* src = (const f32x4*)(coeffs + (((size_t)(i * 512 + o)) << 4));
    f32x4 c0 = src[0], c1 = src[1], c2 = src[2], c3 = src[3];
    u32x4 qa, qb;
    qa[0] = pk(c0[0], c0[1]);
    qa[1] = pk(c0[2], c0[3]);
    qa[2] = pk(c1[0], c1[1]);
    qa[3] = pk(c1[2], c1[3]);
    qb[0] = pk(c2[0], c2[1]);
    qb[1] = pk(c2[2], c2[3]);
    qb[2] = pk(c3[0], c3[1]);
    qb[3] = pk(c3[2], c3[3]);
    size_t cidx = (size_t)(o >> 7) * BT_CHUNKS_PER_CT + (size_t)(2 * i) * 128 + (o & 127);
    u32x4* base = (u32x4*)bt2;
    base[cidx]       = qa;   // kslot 2i   (n=0..7)
    base[cidx + 128] = qb;   // kslot 2i+1 (n=8..15)
  }
  {
    int o2 = tid >> 9, i2 = tid & 511;
    size_t cidx = (size_t)(o2 >> 7) * BT_CHUNKS_PER_CT + (size_t)(1024 + (i2 >> 3)) * 128 + (o2 & 127);
    bt2[cidx * 8 + (i2 & 7)] = (uint16_t)bf_rtn(bw[i2 * 512 + o2]);
  }
  if (tid == 0) out[(size_t)MB_ * OD] = 0.0f;   // kl output
}

// ---------------- phase 3: fused GEMM, register-A, 16 waves -----------------
// C[8192,512] = A[8192,8704] @ B[8704,512].  Tile 128x128, BK=64.
// ROUND-10: 1024 threads / 16 waves (wave tile 16x64) -> 4 waves/SIMD for
// latency hiding; per-wave chain+MFMA work halves. All data paths unchanged
// from the passing round-9 kernel (bt2, stageB identity copy, stageT, chains,
// pk, snapshot-before-prefetch discipline).
__global__ __launch_bounds__(1024, 4) void k_gemm(const float* __restrict__ t,
                                                  const uint16_t* __restrict__ xbf,
                                                  const uint16_t* __restrict__ bt2,
                                                  float* __restrict__ out) {
  __shared__ __align__(128) char lds[36864];  // B dbuf 2x16KB | t dbuf 2x2KB

  const int tid  = threadIdx.x;       // 0..1023
  const int lane = tid & 63;
  const int wid  = tid >> 6;          // 0..15
  const int wr   = wid >> 1;          // 0..7 (row group of 16)
  const int wc   = wid & 1;           // 0..1 (col group of 64)
  const int l15  = lane & 15, l4 = lane >> 4;
  const bool hiH = (l4 & 1) != 0;     // which T-half this lane holds
  const int fq   = l4 >> 1;           // feature sub-offset 0..1

  // bijective XCD swizzle: each XCD gets 8 row-tiles x 4 col-tiles
  int bx  = blockIdx.x;               // 0..255
  int idx = bx >> 3;
  int rt  = (bx & 7) * 8 + (idx >> 2);   // 0..63
  int ct  = idx & 3;                     // 0..3
  const int brow = rt << 7, bcol = ct << 7;

  const char* btbase = (const char*)bt2 + (size_t)ct * BT_BYTES_PER_CT;
  const int row = brow + wr * 16 + l15;              // this lane's A row
  const uint16_t* x0 = xbf + (size_t)row * FD;

  f32x4 acc[4];
#pragma unroll
  for (int n = 0; n < 4; ++n) acc[n] = (f32x4)0.0f;

  auto stageB = [&](int k0, int buf) {  // identity copy from tiled bt2, 16B/thread
    gload_lds16(btbase + (size_t)k0 * 256 + (size_t)tid * 16,
                lds + buf * 16384 + tid * 16);
  };
  // stage t[brow..brow+127][4*stepn .. +4) (2KB) -> LDS t panel
  auto stageT = [&](int stepn, int buf) {
    if (wid < 2) {
      const char* g = (const char*)t +
          (((size_t)(brow + wid * 64 + lane) * FD + (stepn << 2)) << 2);
      gload_lds16(g, lds + 32768 + buf * 2048 + wid * 1024 + lane * 16);
    }
  };

  // Chebyshev chain -> this lane's 8-element fragment (T_{n0}..T_{n0+7})
  auto chainfrag = [&](float tv) -> u32x4 {
    float c2 = tv + tv;
    float T0 = 1.0f, T1 = tv;
    float T2  = __builtin_fmaf(c2, T1,  -T0);
    float T3  = __builtin_fmaf(c2, T2,  -T1);
    float T4  = __builtin_fmaf(c2, T3,  -T2);
    float T5  = __builtin_fmaf(c2, T4,  -T3);
    float T6  = __builtin_fmaf(c2, T5,  -T4);
    float T7  = __builtin_fmaf(c2, T6,  -T5);
    float T8  = __builtin_fmaf(c2, T7,  -T6);
    float T9  = __builtin_fmaf(c2, T8,  -T7);
    float T10 = __builtin_fmaf(c2, T9,  -T8);
    float T11 = __builtin_fmaf(c2, T10, -T9);
    float T12 = __builtin_fmaf(c2, T11, -T10);
    float T13 = __builtin_fmaf(c2, T12, -T11);
    float T14 = __builtin_fmaf(c2, T13, -T12);
    float T15 = __builtin_fmaf(c2, T14, -T13);
    float s0 = hiH ? T8  : T0, s1 = hiH ? T9  : T1;
    float s2 = hiH ? T10 : T2, s3 = hiH ? T11 : T3;
    float s4 = hiH ? T12 : T4, s5 = hiH ? T13 : T5;
    float s6 = hiH ? T14 : T6, s7 = hiH ? T15 : T7;
    u32x4 r;
    r[0] = pk(s0, s1); r[1] = pk(s2, s3);
    r[2] = pk(s4, s5); r[3] = pk(s6, s7);
    return r;
  };

  // prologue: stage B and t for step 0
  stageB(0, 0);
  stageT(0, 0);
  u32x4 pf0 = {}, pf1 = {};           // residual prefetch regs (af[h])

  for (int step = 0; step < 136; ++step) {
    int buf = step & 1;
    bool basis = step < 128;          // KBASIS/64 = 128

    // snapshot THIS step's residual data BEFORE the next prefetch overwrites
    u32x4 af0 = pf0, af1 = pf1;

    __syncthreads();                  // buf fully staged (B + t)

    if (step < 135) {
      stageB((step + 1) << 6, buf ^ 1);
      if (step + 1 < 128) {
        stageT(step + 1, buf ^ 1);
      } else {                        // prefetch xbf frags for next residual step
        int kres = ((step + 1 - 128) << 6) + l4 * 8;
        pf0 = *(const u32x4*)(x0 + kres);
        pf1 = *(const u32x4*)(x0 + kres + 32);
      }
    }

    if (basis) {
      const char* tb = lds + 32768 + buf * 2048;
      int ra = (wr * 16 + l15) * 16;           // row byte base
      float tva = *(const float*)(tb + ra + fq * 4);
      float tvb = *(const float*)(tb + ra + (2 + fq) * 4);
      af0 = chainfrag(tva);
      af1 = chainfrag(tvb);
    }

    const char* bb = lds + buf * 16384;
    bf16x8 b[2][4];
#pragma unroll
    for (int h = 0; h < 2; ++h) {
      int ks = 4 * h + l4;                 // kslot = k/8
#pragma unroll
      for (int n = 0; n < 4; ++n) {
        int bro = wc * 64 + n * 16 + l15;
        b[h][n] = *(const bf16x8*)(bb + ks * 2048 + bro * 16);
      }
    }
    bf16x8 a0 = *(const bf16x8*)&af0;
    bf16x8 a1 = *(const bf16x8*)&af1;
#pragma unroll
    for (int n = 0; n < 4; ++n) {
      acc[n] = __builtin_amdgcn_mfma_f32_16x16x32_bf16(a0, b[0][n], acc[n], 0, 0, 0);
      acc[n] = __builtin_amdgcn_mfma_f32_16x16x32_bf16(a1, b[1][n], acc[n], 0, 0, 0);
    }
  }

  // epilogue: C/D layout col=l&15, row=(l>>4)*4+r  [m89]
#pragma unroll
  for (int n = 0; n < 4; ++n)
#pragma unroll
    for (int r = 0; r < 4; ++r) {
      int grow = brow + wr * 16 + l4 * 4 + r;
      int gcol = bcol + wc * 64 + n * 16 + l15;
      out[(size_t)grow * OD + gcol] = acc[n][r];
    }
}

extern "C" void kernel_launch(void* const* d_in, const int* in_sizes, int n_in,
                              void* d_out, int out_size, void* d_ws, size_t ws_size,
                              hipStream_t stream) {
  const float* x      = (const float*)d_in[0];
  const float* coeffs = (const float*)d_in[1];
  const float* bw     = (const float*)d_in[2];
  float* out = (float*)d_out;
  char* ws = (char*)d_ws;

  float*    t   = (float*)ws;                                  // 16 MB fp32 tanh
  uint16_t* xbf = (uint16_t*)(ws + (size_t)16777216);          // 8 MB bf16 x
  uint16_t* bt2 = (uint16_t*)(ws + (size_t)16777216 + 8388608);// 8.5 MB tiled B

  k_tanh<<<4096, 256, 0, stream>>>(x, t, xbf);
  k_bt<<<1024, 256, 0, stream>>>(coeffs, bw, bt2, out);
  k_gemm<<<256, 1024, 0, stream>>>(t, xbf, bt2, out);
}